// Round 19
// baseline (211.679 us; speedup 1.0000x reference)
//
#include <hip/hip_runtime.h>
#include <hip/hip_bf16.h>
#include <stdint.h>

typedef unsigned short u16;
typedef __attribute__((ext_vector_type(8))) short short8;   // 8 bf16 MFMA operand
typedef __attribute__((ext_vector_type(4))) short short4v;
typedef __attribute__((ext_vector_type(4))) float f4;
typedef __attribute__((ext_vector_type(4))) float f32x4;

static __device__ __forceinline__ u16 f2b(float f) {
  union { float f; uint32_t u; } c; c.f = f;
  return (u16)((c.u + 0x7FFFu + ((c.u >> 16) & 1u)) >> 16);   // RNE
}
static __device__ __forceinline__ float b2f(u16 s) {
  union { uint32_t u; float f; } c; c.u = ((uint32_t)s) << 16; return c.f;
}
static __device__ __forceinline__ uint32_t pk2(float lo, float hi) {
  __hip_bfloat162 b = __float22bfloat162_rn(make_float2(lo, hi));   // RNE = f2b
  union { __hip_bfloat162 b; uint32_t u; } c; c.b = b; return c.u;
}

// ---------------- prep: rows [rowStart, rowStart+BC) of x,h -> bf16 Ab ----
__global__ __launch_bounds__(256) void cvt_kernel(const float* __restrict__ x,
                                                  const float* __restrict__ h,
                                                  u16* __restrict__ Ab,
                                                  int rowStart, int nBlkHalf) {
  bool isH = (int)blockIdx.x >= nBlkHalf;
  int blk = isH ? (blockIdx.x - nBlkHalf) : blockIdx.x;
  const float* src = (isH ? h : x) + (size_t)rowStart * 512;
  u16* dst = Ab + (size_t)rowStart * 512 + (isH ? ((size_t)32768 * 512) : 0);
  size_t e = ((size_t)blk * 256 + threadIdx.x) << 3;

  f4 v0, v1;
  asm volatile(
      "global_load_dwordx4 %0, %2, off\n\t"
      "global_load_dwordx4 %1, %2, off offset:16\n\t"
      "s_waitcnt vmcnt(0)"
      : "=&v"(v0), "=&v"(v1)
      : "v"(src + e)
      : "memory");

  short8 o;
  o[0] = (short)f2b(v0[0]); o[1] = (short)f2b(v0[1]);
  o[2] = (short)f2b(v0[2]); o[3] = (short)f2b(v0[3]);
  o[4] = (short)f2b(v1[0]); o[5] = (short)f2b(v1[1]);
  o[6] = (short)f2b(v1[2]); o[7] = (short)f2b(v1[3]);
  *(short8*)(dst + e) = o;
}

// ---- prep: both weight transposes in one launch ----
__global__ __launch_bounds__(256) void transpose_cat(const float* __restrict__ WA0,
                                                     const float* __restrict__ WB0,
                                                     const float* __restrict__ WA1,
                                                     const float* __restrict__ WB1,
                                                     u16* __restrict__ dst0,
                                                     u16* __restrict__ dst1) {
  __shared__ float t[32][33];
  int n0 = blockIdx.x * 32, k0 = blockIdx.y * 32;
  int tx = threadIdx.x, ty = threadIdx.y;
  const float* srcA = blockIdx.z ? WA1 : WA0;
  const float* srcB = blockIdx.z ? WB1 : WB0;
  u16* dst = blockIdx.z ? dst1 : dst0;
  const float* src; int strideN, nb;
  if (n0 < 1024) { src = srcA; strideN = 1024; nb = n0; }
  else           { src = srcB; strideN = 512;  nb = n0 - 1024; }
#pragma unroll
  for (int i = 0; i < 4; ++i) {
    int k = k0 + ty + i * 8;
    t[tx][ty + i * 8] = src[(size_t)k * strideN + nb + tx];
  }
  __syncthreads();
#pragma unroll
  for (int i = 0; i < 4; ++i) {
    int n = ty + i * 8;
    dst[(size_t)(n0 + n) * 512 + k0 + tx] = f2b(t[n][tx]);
  }
}

// ---------------- GEMM: r19 = 4 super-phases (correctness-minimum barriers)
// r18 post-mortem: 1470 cyc/phase vs ~875 LDS floor; the gap is per-barrier
// wave-skew x8. Hazard audit: only 4 barriers/iteration are required --
// one between each LDS region's last-read and its next write-issue:
//   S1 writes b1.A (last read prev S4)   S2 writes b0.B (last read S1)
//   S3 writes b0.A (last read S2)        S4 writes b1.B (last read S3)
// Counted vmcnt: S2 vmcnt(4) forces A(2t+1) [b1.A]; S4 vmcnt(4) forces
// B(2t+2)+A(2t+2) [b0], leaves B(2t+3) in flight. Prologue leaves B(1) in
// flight (identical to r17/r18). Each super-phase: reads -> staging-issue ->
// barrier -> 32 MFMAs.
#define AS1 __attribute__((address_space(1)))
#define AS3 __attribute__((address_space(3)))
#define MF __builtin_amdgcn_mfma_f32_16x16x32_bf16

__global__ __launch_bounds__(512, 2) void gemm_kernel(
    const u16* __restrict__ Ab, const u16* __restrict__ WxT,
    const u16* __restrict__ WhT, u16* __restrict__ Cb,
    int rowStartX, int rowStartH, int tilesPerHalf) {
  __shared__ u16 lds[65536];   // K-loop: 2 x 32768-u16 bufs; epilogue: T[128][264]

  int tid = threadIdx.x, lane = tid & 63, wv = tid >> 6;
  int wm = wv >> 2, wn = wv & 3;                 // 2M x 4N
  int l15 = lane & 15, l4 = lane >> 4, l7 = lane & 7;

  int nwg = gridDim.x, bid = blockIdx.x;
  int swz = (nwg & 7) ? bid : ((bid & 7) * (nwg >> 3) + (bid >> 3));
  int mb = swz / 6, nb = swz - mb * 6;
  size_t m0; const u16* Wt;
  if (mb < tilesPerHalf) { m0 = (size_t)rowStartX + (size_t)mb * 256; Wt = WxT; }
  else { m0 = (size_t)rowStartH + (size_t)(mb - tilesPerHalf) * 256; Wt = WhT; }
  int crow0 = mb * 256, n0 = nb * 256;
  const u16* At = Ab + m0 * 512;
  const u16* Bt = Wt + (size_t)n0 * 512;

#define UNIT(tbase, row0, kt, dstoff) do { \
    _Pragma("unroll") \
    for (int i_ = 0; i_ < 2; ++i_) { \
      int si_ = i_ * 512 + tid; \
      int r_ = si_ >> 3, s_ = si_ & 7; \
      int g_ = s_ ^ (r_ & 7); \
      __builtin_amdgcn_global_load_lds( \
          (const AS1 void*)((tbase) + (size_t)((row0) + r_) * 512 + (kt) * 64 + g_ * 8), \
          (AS3 void*)(lds + (dstoff) + si_ * 8), 16, 0, 0); \
    } \
  } while (0)

#define LDA(bufo, q, mr, ks) \
  (*(const short8*)(lds + (bufo) + (wm * 128 + (q) * 32 + (mr) * 16 + l15) * 64 + \
                    ((((ks) * 4 + l4) ^ l7) << 3)))
#define LDB(bufo, f, ks) \
  (*(const short8*)(lds + (bufo) + 16384 + (wn * 64 + (f) * 16 + l15) * 64 + \
                    ((((ks) * 4 + l4) ^ l7) << 3)))

#define BARSEQ asm volatile("s_barrier" ::: "memory")

#define MFMAQ(q, A00, A10, A01, A11) do { \
    __builtin_amdgcn_s_setprio(1); \
    _Pragma("unroll") for (int f_ = 0; f_ < 4; ++f_) \
      acc[(q)*2][f_]   = MF(br[f_][0], A00, acc[(q)*2][f_], 0, 0, 0); \
    _Pragma("unroll") for (int f_ = 0; f_ < 4; ++f_) \
      acc[(q)*2+1][f_] = MF(br[f_][0], A10, acc[(q)*2+1][f_], 0, 0, 0); \
    _Pragma("unroll") for (int f_ = 0; f_ < 4; ++f_) \
      acc[(q)*2][f_]   = MF(br[f_][1], A01, acc[(q)*2][f_], 0, 0, 0); \
    _Pragma("unroll") for (int f_ = 0; f_ < 4; ++f_) \
      acc[(q)*2+1][f_] = MF(br[f_][1], A11, acc[(q)*2+1][f_], 0, 0, 0); \
    __builtin_amdgcn_s_setprio(0); \
  } while (0)

  f32x4 acc[8][4] = {};

  // prologue: A(0)->b0.A, B(0)->b0.B, B(1)->b1.B; vmcnt(4) leaves B(1) in flight
  UNIT(At, 0,   0, 0);     UNIT(At, 128, 0, 8192);
  UNIT(Bt, 0,   0, 16384); UNIT(Bt, 128, 0, 24576);
  UNIT(Bt, 0,   1, 32768 + 16384); UNIT(Bt, 128, 1, 32768 + 24576);
  asm volatile("s_waitcnt vmcnt(4)" ::: "memory");
  BARSEQ;

#pragma unroll
  for (int t = 0; t < 4; ++t) {
    const int b0 = 0, b1 = 32768;
    const int k1 = 2 * t + 1;
    const bool st = (t < 3);
    short8 br[4][2];
    { // S1: b0 B-frags + A q0,q1; stage A(2t+1) -> b1.A (sealed at prev S4-end)
#pragma unroll
      for (int f_ = 0; f_ < 4; ++f_) { br[f_][0] = LDB(b0, f_, 0); br[f_][1] = LDB(b0, f_, 1); }
      short8 c00 = LDA(b0, 0, 0, 0), c01 = LDA(b0, 0, 1, 0),
             c02 = LDA(b0, 0, 0, 1), c03 = LDA(b0, 0, 1, 1);
      short8 c10 = LDA(b0, 1, 0, 0), c11 = LDA(b0, 1, 1, 0),
             c12 = LDA(b0, 1, 0, 1), c13 = LDA(b0, 1, 1, 1);
      UNIT(At, 0, k1, b1 + 0); UNIT(At, 128, k1, b1 + 8192);
      BARSEQ;
      MFMAQ(0, c00, c01, c02, c03);
      MFMAQ(1, c10, c11, c12, c13);
    }
    { // S2: A q2,q3 (b0); stage B(2t+2) -> b0.B (S1 reads sealed);
      // vmcnt(4) forces A(2t+1) resident (collectivized by barrier)
      short8 c20 = LDA(b0, 2, 0, 0), c21 = LDA(b0, 2, 1, 0),
             c22 = LDA(b0, 2, 0, 1), c23 = LDA(b0, 2, 1, 1);
      short8 c30 = LDA(b0, 3, 0, 0), c31 = LDA(b0, 3, 1, 0),
             c32 = LDA(b0, 3, 0, 1), c33 = LDA(b0, 3, 1, 1);
      if (st) { UNIT(Bt, 0, k1 + 1, b0 + 16384); UNIT(Bt, 128, k1 + 1, b0 + 24576);
                asm volatile("s_waitcnt vmcnt(4)" ::: "memory"); }
      else    { asm volatile("s_waitcnt vmcnt(0)" ::: "memory"); }
      BARSEQ;
      MFMAQ(2, c20, c21, c22, c23);
      MFMAQ(3, c30, c31, c32, c33);
    }
    { // S3: b1 B-frags + A q0,q1; stage A(2t+2) -> b0.A (S2 reads sealed)
#pragma unroll
      for (int f_ = 0; f_ < 4; ++f_) { br[f_][0] = LDB(b1, f_, 0); br[f_][1] = LDB(b1, f_, 1); }
      short8 c00 = LDA(b1, 0, 0, 0), c01 = LDA(b1, 0, 1, 0),
             c02 = LDA(b1, 0, 0, 1), c03 = LDA(b1, 0, 1, 1);
      short8 c10 = LDA(b1, 1, 0, 0), c11 = LDA(b1, 1, 1, 0),
             c12 = LDA(b1, 1, 0, 1), c13 = LDA(b1, 1, 1, 1);
      if (st) { UNIT(At, 0, k1 + 1, b0 + 0); UNIT(At, 128, k1 + 1, b0 + 8192); }
      BARSEQ;
      MFMAQ(0, c00, c01, c02, c03);
      MFMAQ(1, c10, c11, c12, c13);
    }
    { // S4: A q2,q3 (b1); stage B(2t+3) -> b1.B (S3 reads sealed);
      // vmcnt(4) forces B(2t+2)+A(2t+2) [b0 complete], leaves B(2t+3) in flight
      short8 c20 = LDA(b1, 2, 0, 0), c21 = LDA(b1, 2, 1, 0),
             c22 = LDA(b1, 2, 0, 1), c23 = LDA(b1, 2, 1, 1);
      short8 c30 = LDA(b1, 3, 0, 0), c31 = LDA(b1, 3, 1, 0),
             c32 = LDA(b1, 3, 0, 1), c33 = LDA(b1, 3, 1, 1);
      if (st) { UNIT(Bt, 0, k1 + 2, b1 + 16384); UNIT(Bt, 128, k1 + 2, b1 + 24576);
                asm volatile("s_waitcnt vmcnt(4)" ::: "memory"); }
      BARSEQ;
      MFMAQ(2, c20, c21, c22, c23);
      MFMAQ(3, c30, c31, c32, c33);
    }
  }
#undef UNIT
#undef LDA
#undef LDB
#undef MFMAQ

  // ---- r13 coalesced C-store via LDS transpose ----
  const int TP = 264;
#pragma unroll
  for (int pass = 0; pass < 2; ++pass) {
    BARSEQ;
    if (wm == pass) {
#pragma unroll
      for (int mr = 0; mr < 8; ++mr) {
        int ml = mr * 16 + l15;
#pragma unroll
        for (int nr = 0; nr < 4; ++nr) {
          int c4 = wn * 16 + nr * 4 + l4;
          uint2 w;
          w.x = pk2(acc[mr][nr][0], acc[mr][nr][1]);
          w.y = pk2(acc[mr][nr][2], acc[mr][nr][3]);
          *(uint2*)(lds + ml * TP + c4 * 4) = w;
        }
      }
    }
    asm volatile("s_waitcnt lgkmcnt(0)" ::: "memory");
    BARSEQ;
    int row = tid >> 2;
    int q = tid & 3;
    size_t gbase = (size_t)(crow0 + pass * 128 + row) * 1536 + n0;
#pragma unroll
    for (int j = 0; j < 8; ++j) {
      int c8 = q + 4 * j;
      short8 v = *(const short8*)(lds + row * TP + c8 * 8);
      *(short8*)(Cb + gbase + c8 * 8) = v;
    }
  }
#undef BARSEQ
}

// ---------------- epilogue: bias + 4x LN + gates + output ----------------
__global__ __launch_bounds__(256) void epi_kernel(
    const u16* __restrict__ Cb, const float* __restrict__ h,
    const float* __restrict__ b_i2h, const float* __restrict__ b_h2h,
    const float* __restrict__ b_hatW, const float* __restrict__ b_hatU,
    float* __restrict__ out, int mBase, int BC) {
  int wv = threadIdx.x >> 6;
  int lane = threadIdx.x & 63;
  int mLocal = blockIdx.x * 4 + wv;
  size_t mGlob = (size_t)mBase + mLocal;
  const u16* Ar = Cb + (size_t)mLocal * 1536;
  const u16* Br = Cb + ((size_t)BC + mLocal) * 1536;
  int j0 = lane * 8;

  float a[3][8], b[3][8];
#pragma unroll
  for (int c = 0; c < 3; ++c) {
    short8 va = __builtin_nontemporal_load((const short8*)(Ar + c * 512 + j0));
    short8 vb = __builtin_nontemporal_load((const short8*)(Br + c * 512 + j0));
    const float* biasA = (c == 0) ? (b_i2h + j0) : (c == 1) ? (b_i2h + 512 + j0) : (b_hatW + j0);
    const float* biasB = (c == 0) ? (b_h2h + j0) : (c == 1) ? (b_h2h + 512 + j0) : (b_hatU + j0);
    f4 ba0 = *(const f4*)biasA, ba1 = *(const f4*)(biasA + 4);
    f4 bb0 = *(const f4*)biasB, bb1 = *(const f4*)(biasB + 4);
#pragma unroll
    for (int j = 0; j < 4; ++j) {
      a[c][j]     = b2f((u16)va[j])     + ba0[j];
      a[c][j + 4] = b2f((u16)va[j + 4]) + ba1[j];
      b[c][j]     = b2f((u16)vb[j])     + bb0[j];
      b[c][j + 4] = b2f((u16)vb[j + 4]) + bb1[j];
    }
  }

  float s1a = 0, q1a = 0, s2a = 0, q2a = 0, s1b = 0, q1b = 0, s2b = 0, q2b = 0;
#pragma unroll
  for (int j = 0; j < 8; ++j) {
    s1a += a[0][j] + a[1][j]; q1a += a[0][j] * a[0][j] + a[1][j] * a[1][j];
    s2a += a[2][j];           q2a += a[2][j] * a[2][j];
    s1b += b[0][j] + b[1][j]; q1b += b[0][j] * b[0][j] + b[1][j] * b[1][j];
    s2b += b[2][j];           q2b += b[2][j] * b[2][j];
  }
#pragma unroll
  for (int off = 32; off > 0; off >>= 1) {
    s1a += __shfl_xor(s1a, off); q1a += __shfl_xor(q1a, off);
    s2a += __shfl_xor(s2a, off); q2a += __shfl_xor(q2a, off);
    s1b += __shfl_xor(s1b, off); q1b += __shfl_xor(q1b, off);
    s2b += __shfl_xor(s2b, off); q2b += __shfl_xor(q2b, off);
  }
  const float inv1 = 1.0f / 1024.0f, inv2 = 1.0f / 512.0f, eps = 1e-5f;
  float mu1a = s1a * inv1, mu2a = s2a * inv2, mu1b = s1b * inv1, mu2b = s2b * inv2;
  float rs1a = rsqrtf(q1a * inv1 - mu1a * mu1a + eps);
  float rs2a = rsqrtf(q2a * inv2 - mu2a * mu2a + eps);
  float rs1b = rsqrtf(q1b * inv1 - mu1b * mu1b + eps);
  float rs2b = rsqrtf(q2b * inv2 - mu2b * mu2b + eps);

  const float* hrow = h + mGlob * 512 + j0;
  f4 h0 = *(const f4*)hrow, h1 = *(const f4*)(hrow + 4);
  f4 o0, o1;
#pragma unroll
  for (int j = 0; j < 8; ++j) {
    float zs  = (a[0][j] - mu1a) * rs1a + (b[0][j] - mu1b) * rs1b;
    float rsg = (a[1][j] - mu1a) * rs1a + (b[1][j] - mu1b) * rs1b;
    float z = 1.0f / (1.0f + __expf(-zs));
    float r = 1.0f / (1.0f + __expf(-rsg));
    float hh = tanhf((a[2][j] - mu2a) * rs2a + r * ((b[2][j] - mu2b) * rs2b));
    float hv = (j < 4) ? h0[j] : h1[j - 4];
    float o = hv + z * (hh - hv);
    if (j < 4) o0[j] = o; else o1[j - 4] = o;
  }
  __builtin_nontemporal_store(o0, (f4*)(out + mGlob * 512 + j0));
  __builtin_nontemporal_store(o1, (f4*)(out + mGlob * 512 + j0 + 4));
}

extern "C" void kernel_launch(void* const* d_in, const int* in_sizes, int n_in,
                              void* d_out, int out_size, void* d_ws, size_t ws_size,
                              hipStream_t stream) {
  const float* x      = (const float*)d_in[0];
  const float* h      = (const float*)d_in[1];
  const float* W_i2h  = (const float*)d_in[2];
  const float* b_i2h  = (const float*)d_in[3];
  const float* W_h2h  = (const float*)d_in[4];
  const float* b_h2h  = (const float*)d_in[5];
  const float* W_hatW = (const float*)d_in[6];
  const float* b_hatW = (const float*)d_in[7];
  const float* W_hatU = (const float*)d_in[8];
  const float* b_hatU = (const float*)d_in[9];
  float* out = (float*)d_out;

  u16* WxT = (u16*)d_ws;                       // [1536][512]
  u16* WhT = WxT + (size_t)1536 * 512;         // [1536][512]
  u16* Ab  = WhT + (size_t)1536 * 512;         // [65536][512] = bf16(x);bf16(h)
  u16* Cb  = Ab + (size_t)65536 * 512;         // [2*BC][1536] chunk buffer

  size_t fixedElems = (size_t)2 * 1536 * 512 + (size_t)65536 * 512;
  int chunks = 2;
  for (;;) {
    size_t need = (fixedElems + (size_t)2 * (32768 / chunks) * 1536) * sizeof(u16);
    if (need <= ws_size || chunks >= 128) break;
    chunks <<= 1;
  }
  int BC = 32768 / chunks;
  int tph = BC / 256;
  int nwg = 2 * tph * 6;
  int nBlkHalf = BC / 4;

  transpose_cat<<<dim3(48, 16, 2), dim3(32, 8), 0, stream>>>(
      W_i2h, W_hatW, W_h2h, W_hatU, WxT, WhT);
  for (int cc = 0; cc < chunks; ++cc) {
    cvt_kernel<<<2 * nBlkHalf, 256, 0, stream>>>(x, h, Ab, cc * BC, nBlkHalf);
    gemm_kernel<<<nwg, 512, 0, stream>>>(Ab, WxT, WhT, Cb,
                                         cc * BC, 32768 + cc * BC, tph);
    epi_kernel<<<BC / 4, 256, 0, stream>>>(Cb, h, b_i2h, b_h2h, b_hatW, b_hatU,
                                           out, cc * BC, BC);
  }
}

// Round 20
// 209.720 us; speedup vs baseline: 1.0093x; 1.0093x over previous
//
#include <hip/hip_runtime.h>
#include <hip/hip_bf16.h>
#include <stdint.h>

typedef unsigned short u16;
typedef __attribute__((ext_vector_type(8))) short short8;   // 8 bf16 MFMA operand
typedef __attribute__((ext_vector_type(4))) short short4v;
typedef __attribute__((ext_vector_type(4))) float f4;
typedef __attribute__((ext_vector_type(4))) float f32x4;

static __device__ __forceinline__ u16 f2b(float f) {
  union { float f; uint32_t u; } c; c.f = f;
  return (u16)((c.u + 0x7FFFu + ((c.u >> 16) & 1u)) >> 16);   // RNE
}
static __device__ __forceinline__ float b2f(u16 s) {
  union { uint32_t u; float f; } c; c.u = ((uint32_t)s) << 16; return c.f;
}
static __device__ __forceinline__ uint32_t pk2(float lo, float hi) {
  __hip_bfloat162 b = __float22bfloat162_rn(make_float2(lo, hi));   // RNE = f2b
  union { __hip_bfloat162 b; uint32_t u; } c; c.b = b; return c.u;
}

// ---------------- prep: rows [rowStart, rowStart+BC) of x,h -> bf16 Ab ----
__global__ __launch_bounds__(256) void cvt_kernel(const float* __restrict__ x,
                                                  const float* __restrict__ h,
                                                  u16* __restrict__ Ab,
                                                  int rowStart, int nBlkHalf) {
  bool isH = (int)blockIdx.x >= nBlkHalf;
  int blk = isH ? (blockIdx.x - nBlkHalf) : blockIdx.x;
  const float* src = (isH ? h : x) + (size_t)rowStart * 512;
  u16* dst = Ab + (size_t)rowStart * 512 + (isH ? ((size_t)32768 * 512) : 0);
  size_t e = ((size_t)blk * 256 + threadIdx.x) << 3;

  f4 v0, v1;
  asm volatile(
      "global_load_dwordx4 %0, %2, off\n\t"
      "global_load_dwordx4 %1, %2, off offset:16\n\t"
      "s_waitcnt vmcnt(0)"
      : "=&v"(v0), "=&v"(v1)
      : "v"(src + e)
      : "memory");

  short8 o;
  o[0] = (short)f2b(v0[0]); o[1] = (short)f2b(v0[1]);
  o[2] = (short)f2b(v0[2]); o[3] = (short)f2b(v0[3]);
  o[4] = (short)f2b(v1[0]); o[5] = (short)f2b(v1[1]);
  o[6] = (short)f2b(v1[2]); o[7] = (short)f2b(v1[3]);
  *(short8*)(dst + e) = o;
}

// ---- prep: both weight transposes in one launch ----
__global__ __launch_bounds__(256) void transpose_cat(const float* __restrict__ WA0,
                                                     const float* __restrict__ WB0,
                                                     const float* __restrict__ WA1,
                                                     const float* __restrict__ WB1,
                                                     u16* __restrict__ dst0,
                                                     u16* __restrict__ dst1) {
  __shared__ float t[32][33];
  int n0 = blockIdx.x * 32, k0 = blockIdx.y * 32;
  int tx = threadIdx.x, ty = threadIdx.y;
  const float* srcA = blockIdx.z ? WA1 : WA0;
  const float* srcB = blockIdx.z ? WB1 : WB0;
  u16* dst = blockIdx.z ? dst1 : dst0;
  const float* src; int strideN, nb;
  if (n0 < 1024) { src = srcA; strideN = 1024; nb = n0; }
  else           { src = srcB; strideN = 512;  nb = n0 - 1024; }
#pragma unroll
  for (int i = 0; i < 4; ++i) {
    int k = k0 + ty + i * 8;
    t[tx][ty + i * 8] = src[(size_t)k * strideN + nb + tx];
  }
  __syncthreads();
#pragma unroll
  for (int i = 0; i < 4; ++i) {
    int n = ty + i * 8;
    dst[(size_t)(n0 + n) * 512 + k0 + tx] = f2b(t[n][tx]);
  }
}

// ---------------- GEMM: r18 (best measured: 8-phase, unpinned barriers) ----
#define AS1 __attribute__((address_space(1)))
#define AS3 __attribute__((address_space(3)))
#define MF __builtin_amdgcn_mfma_f32_16x16x32_bf16

__global__ __launch_bounds__(512, 2) void gemm_kernel(
    const u16* __restrict__ Ab, const u16* __restrict__ WxT,
    const u16* __restrict__ WhT, u16* __restrict__ Cb,
    int rowStartX, int rowStartH, int tilesPerHalf) {
  __shared__ u16 lds[65536];   // K-loop: 2 x 32768-u16 bufs; epilogue: T[128][264]

  int tid = threadIdx.x, lane = tid & 63, wv = tid >> 6;
  int wm = wv >> 2, wn = wv & 3;                 // 2M x 4N
  int l15 = lane & 15, l4 = lane >> 4, l7 = lane & 7;

  int nwg = gridDim.x, bid = blockIdx.x;
  int swz = (nwg & 7) ? bid : ((bid & 7) * (nwg >> 3) + (bid >> 3));
  int mb = swz / 6, nb = swz - mb * 6;
  size_t m0; const u16* Wt;
  if (mb < tilesPerHalf) { m0 = (size_t)rowStartX + (size_t)mb * 256; Wt = WxT; }
  else { m0 = (size_t)rowStartH + (size_t)(mb - tilesPerHalf) * 256; Wt = WhT; }
  int crow0 = mb * 256, n0 = nb * 256;
  const u16* At = Ab + m0 * 512;
  const u16* Bt = Wt + (size_t)n0 * 512;

#define UNIT(tbase, row0, kt, dstoff) do { \
    _Pragma("unroll") \
    for (int i_ = 0; i_ < 2; ++i_) { \
      int si_ = i_ * 512 + tid; \
      int r_ = si_ >> 3, s_ = si_ & 7; \
      int g_ = s_ ^ (r_ & 7); \
      __builtin_amdgcn_global_load_lds( \
          (const AS1 void*)((tbase) + (size_t)((row0) + r_) * 512 + (kt) * 64 + g_ * 8), \
          (AS3 void*)(lds + (dstoff) + si_ * 8), 16, 0, 0); \
    } \
  } while (0)

#define LDA(bufo, q, mr, ks) \
  (*(const short8*)(lds + (bufo) + (wm * 128 + (q) * 32 + (mr) * 16 + l15) * 64 + \
                    ((((ks) * 4 + l4) ^ l7) << 3)))
#define LDB(bufo, f, ks) \
  (*(const short8*)(lds + (bufo) + 16384 + (wn * 64 + (f) * 16 + l15) * 64 + \
                    ((((ks) * 4 + l4) ^ l7) << 3)))

#define BARSEQ asm volatile("s_barrier" ::: "memory")

#define MFMAQ(q, A00, A10, A01, A11) do { \
    __builtin_amdgcn_s_setprio(1); \
    _Pragma("unroll") for (int f_ = 0; f_ < 4; ++f_) \
      acc[(q)*2][f_]   = MF(br[f_][0], A00, acc[(q)*2][f_], 0, 0, 0); \
    _Pragma("unroll") for (int f_ = 0; f_ < 4; ++f_) \
      acc[(q)*2+1][f_] = MF(br[f_][0], A10, acc[(q)*2+1][f_], 0, 0, 0); \
    _Pragma("unroll") for (int f_ = 0; f_ < 4; ++f_) \
      acc[(q)*2][f_]   = MF(br[f_][1], A01, acc[(q)*2][f_], 0, 0, 0); \
    _Pragma("unroll") for (int f_ = 0; f_ < 4; ++f_) \
      acc[(q)*2+1][f_] = MF(br[f_][1], A11, acc[(q)*2+1][f_], 0, 0, 0); \
    __builtin_amdgcn_s_setprio(0); \
  } while (0)

#define PH(bufo, q) \
    short8 a00 = LDA(bufo, q, 0, 0), a10 = LDA(bufo, q, 1, 0), \
           a01 = LDA(bufo, q, 0, 1), a11 = LDA(bufo, q, 1, 1)

  f32x4 acc[8][4] = {};

  UNIT(At, 0,   0, 0);     UNIT(At, 128, 0, 8192);
  UNIT(Bt, 0,   0, 16384); UNIT(Bt, 128, 0, 24576);
  UNIT(Bt, 0,   1, 32768 + 16384); UNIT(Bt, 128, 1, 32768 + 24576);
  asm volatile("s_waitcnt vmcnt(4)" ::: "memory");
  BARSEQ;

#pragma unroll
  for (int t = 0; t < 4; ++t) {
    const int b0 = 0, b1 = 32768;
    const int k1 = 2 * t + 1;
    const bool st = (t < 3);
    short8 br[4][2];
    { // P1
#pragma unroll
      for (int f_ = 0; f_ < 4; ++f_) { br[f_][0] = LDB(b0, f_, 0); br[f_][1] = LDB(b0, f_, 1); }
      PH(b0, 0);
      UNIT(At, 0, k1, b1 + 0);
      BARSEQ; MFMAQ(0, a00, a10, a01, a11);
    }
    { // P2
      PH(b0, 1);
      UNIT(At, 128, k1, b1 + 8192);
      BARSEQ; MFMAQ(1, a00, a10, a01, a11);
    }
    { // P3
      PH(b0, 2);
      if (st) UNIT(Bt, 0, k1 + 1, b0 + 16384);
      BARSEQ; MFMAQ(2, a00, a10, a01, a11);
    }
    { // P4
      PH(b0, 3);
      if (st) { UNIT(Bt, 128, k1 + 1, b0 + 24576);
                asm volatile("s_waitcnt vmcnt(4)" ::: "memory"); }
      else    { asm volatile("s_waitcnt vmcnt(0)" ::: "memory"); }
      BARSEQ; MFMAQ(3, a00, a10, a01, a11);
    }
    { // P5
#pragma unroll
      for (int f_ = 0; f_ < 4; ++f_) { br[f_][0] = LDB(b1, f_, 0); br[f_][1] = LDB(b1, f_, 1); }
      PH(b1, 0);
      if (st) UNIT(At, 0, k1 + 1, b0 + 0);
      BARSEQ; MFMAQ(0, a00, a10, a01, a11);
    }
    { // P6
      PH(b1, 1);
      if (st) UNIT(At, 128, k1 + 1, b0 + 8192);
      BARSEQ; MFMAQ(1, a00, a10, a01, a11);
    }
    { // P7
      PH(b1, 2);
      if (st) UNIT(Bt, 0, k1 + 2, b1 + 16384);
      BARSEQ; MFMAQ(2, a00, a10, a01, a11);
    }
    { // P8
      PH(b1, 3);
      if (st) { UNIT(Bt, 128, k1 + 2, b1 + 24576);
                asm volatile("s_waitcnt vmcnt(4)" ::: "memory"); }
      BARSEQ; MFMAQ(3, a00, a10, a01, a11);
    }
  }
#undef UNIT
#undef LDA
#undef LDB
#undef MFMAQ
#undef PH

  // ---- r13 coalesced C-store via LDS transpose ----
  const int TP = 264;
#pragma unroll
  for (int pass = 0; pass < 2; ++pass) {
    BARSEQ;
    if (wm == pass) {
#pragma unroll
      for (int mr = 0; mr < 8; ++mr) {
        int ml = mr * 16 + l15;
#pragma unroll
        for (int nr = 0; nr < 4; ++nr) {
          int c4 = wn * 16 + nr * 4 + l4;
          uint2 w;
          w.x = pk2(acc[mr][nr][0], acc[mr][nr][1]);
          w.y = pk2(acc[mr][nr][2], acc[mr][nr][3]);
          *(uint2*)(lds + ml * TP + c4 * 4) = w;
        }
      }
    }
    asm volatile("s_waitcnt lgkmcnt(0)" ::: "memory");
    BARSEQ;
    int row = tid >> 2;
    int q = tid & 3;
    size_t gbase = (size_t)(crow0 + pass * 128 + row) * 1536 + n0;
#pragma unroll
    for (int j = 0; j < 8; ++j) {
      int c8 = q + 4 * j;
      short8 v = *(const short8*)(lds + row * TP + c8 * 8);
      *(short8*)(Cb + gbase + c8 * 8) = v;
    }
  }
#undef BARSEQ
}

// ---------------- epilogue: bias + 4x LN + gates + output ----------------
// r20: h read from Ab's bf16 h-half (33.5MB instead of 67MB f32; written by
// cvt this chunk, L3-warm). Error budget: h only enters as (1-z)*h; bf16
// rel-err 2^-9 on N(0,1) adds <=0.009 abs (0.031 -> <=0.045 << 0.0956).
__global__ __launch_bounds__(256) void epi_kernel(
    const u16* __restrict__ Cb, const u16* __restrict__ Hb,
    const float* __restrict__ b_i2h, const float* __restrict__ b_h2h,
    const float* __restrict__ b_hatW, const float* __restrict__ b_hatU,
    float* __restrict__ out, int mBase, int BC) {
  int wv = threadIdx.x >> 6;
  int lane = threadIdx.x & 63;
  int mLocal = blockIdx.x * 4 + wv;
  size_t mGlob = (size_t)mBase + mLocal;
  const u16* Ar = Cb + (size_t)mLocal * 1536;
  const u16* Br = Cb + ((size_t)BC + mLocal) * 1536;
  int j0 = lane * 8;

  float a[3][8], b[3][8];
#pragma unroll
  for (int c = 0; c < 3; ++c) {
    short8 va = __builtin_nontemporal_load((const short8*)(Ar + c * 512 + j0));
    short8 vb = __builtin_nontemporal_load((const short8*)(Br + c * 512 + j0));
    const float* biasA = (c == 0) ? (b_i2h + j0) : (c == 1) ? (b_i2h + 512 + j0) : (b_hatW + j0);
    const float* biasB = (c == 0) ? (b_h2h + j0) : (c == 1) ? (b_h2h + 512 + j0) : (b_hatU + j0);
    f4 ba0 = *(const f4*)biasA, ba1 = *(const f4*)(biasA + 4);
    f4 bb0 = *(const f4*)biasB, bb1 = *(const f4*)(biasB + 4);
#pragma unroll
    for (int j = 0; j < 4; ++j) {
      a[c][j]     = b2f((u16)va[j])     + ba0[j];
      a[c][j + 4] = b2f((u16)va[j + 4]) + ba1[j];
      b[c][j]     = b2f((u16)vb[j])     + bb0[j];
      b[c][j + 4] = b2f((u16)vb[j + 4]) + bb1[j];
    }
  }

  float s1a = 0, q1a = 0, s2a = 0, q2a = 0, s1b = 0, q1b = 0, s2b = 0, q2b = 0;
#pragma unroll
  for (int j = 0; j < 8; ++j) {
    s1a += a[0][j] + a[1][j]; q1a += a[0][j] * a[0][j] + a[1][j] * a[1][j];
    s2a += a[2][j];           q2a += a[2][j] * a[2][j];
    s1b += b[0][j] + b[1][j]; q1b += b[0][j] * b[0][j] + b[1][j] * b[1][j];
    s2b += b[2][j];           q2b += b[2][j] * b[2][j];
  }
#pragma unroll
  for (int off = 32; off > 0; off >>= 1) {
    s1a += __shfl_xor(s1a, off); q1a += __shfl_xor(q1a, off);
    s2a += __shfl_xor(s2a, off); q2a += __shfl_xor(q2a, off);
    s1b += __shfl_xor(s1b, off); q1b += __shfl_xor(q1b, off);
    s2b += __shfl_xor(s2b, off); q2b += __shfl_xor(q2b, off);
  }
  const float inv1 = 1.0f / 1024.0f, inv2 = 1.0f / 512.0f, eps = 1e-5f;
  float mu1a = s1a * inv1, mu2a = s2a * inv2, mu1b = s1b * inv1, mu2b = s2b * inv2;
  float rs1a = rsqrtf(q1a * inv1 - mu1a * mu1a + eps);
  float rs2a = rsqrtf(q2a * inv2 - mu2a * mu2a + eps);
  float rs1b = rsqrtf(q1b * inv1 - mu1b * mu1b + eps);
  float rs2b = rsqrtf(q2b * inv2 - mu2b * mu2b + eps);

  short8 hv8 = *(const short8*)(Hb + mGlob * 512 + j0);   // bf16 h row (L3-warm)
  f4 o0, o1;
#pragma unroll
  for (int j = 0; j < 8; ++j) {
    float zs  = (a[0][j] - mu1a) * rs1a + (b[0][j] - mu1b) * rs1b;
    float rsg = (a[1][j] - mu1a) * rs1a + (b[1][j] - mu1b) * rs1b;
    float z = 1.0f / (1.0f + __expf(-zs));
    float r = 1.0f / (1.0f + __expf(-rsg));
    float hh = tanhf((a[2][j] - mu2a) * rs2a + r * ((b[2][j] - mu2b) * rs2b));
    float hv = b2f((u16)hv8[j]);
    float o = hv + z * (hh - hv);
    if (j < 4) o0[j] = o; else o1[j - 4] = o;
  }
  __builtin_nontemporal_store(o0, (f4*)(out + mGlob * 512 + j0));
  __builtin_nontemporal_store(o1, (f4*)(out + mGlob * 512 + j0 + 4));
}

extern "C" void kernel_launch(void* const* d_in, const int* in_sizes, int n_in,
                              void* d_out, int out_size, void* d_ws, size_t ws_size,
                              hipStream_t stream) {
  const float* x      = (const float*)d_in[0];
  const float* h      = (const float*)d_in[1];
  const float* W_i2h  = (const float*)d_in[2];
  const float* b_i2h  = (const float*)d_in[3];
  const float* W_h2h  = (const float*)d_in[4];
  const float* b_h2h  = (const float*)d_in[5];
  const float* W_hatW = (const float*)d_in[6];
  const float* b_hatW = (const float*)d_in[7];
  const float* W_hatU = (const float*)d_in[8];
  const float* b_hatU = (const float*)d_in[9];
  float* out = (float*)d_out;

  u16* WxT = (u16*)d_ws;                       // [1536][512]
  u16* WhT = WxT + (size_t)1536 * 512;         // [1536][512]
  u16* Ab  = WhT + (size_t)1536 * 512;         // [65536][512] = bf16(x);bf16(h)
  u16* Cb  = Ab + (size_t)65536 * 512;         // [2*BC][1536] chunk buffer
  u16* Hb  = Ab + (size_t)32768 * 512;         // bf16(h) half of Ab

  size_t fixedElems = (size_t)2 * 1536 * 512 + (size_t)65536 * 512;
  int chunks = 2;
  for (;;) {
    size_t need = (fixedElems + (size_t)2 * (32768 / chunks) * 1536) * sizeof(u16);
    if (need <= ws_size || chunks >= 128) break;
    chunks <<= 1;
  }
  int BC = 32768 / chunks;
  int tph = BC / 256;
  int nwg = 2 * tph * 6;
  int nBlkHalf = BC / 4;

  transpose_cat<<<dim3(48, 16, 2), dim3(32, 8), 0, stream>>>(
      W_i2h, W_hatW, W_h2h, W_hatU, WxT, WhT);
  for (int cc = 0; cc < chunks; ++cc) {
    cvt_kernel<<<2 * nBlkHalf, 256, 0, stream>>>(x, h, Ab, cc * BC, nBlkHalf);
    gemm_kernel<<<nwg, 512, 0, stream>>>(Ab, WxT, WhT, Cb,
                                         cc * BC, 32768 + cc * BC, tph);
    epi_kernel<<<BC / 4, 256, 0, stream>>>(Cb, Hb, b_i2h, b_h2h, b_hatW, b_hatU,
                                           out, cc * BC, BC);
  }
}